// Round 1
// baseline (603.486 us; speedup 1.0000x reference)
//
#include <hip/hip_runtime.h>
#include <cstdint>
#include <cstddef>

#define N_NODES 16384
#define N_EDGES 65536
#define NFEAT 128   // GRU hidden
#define NIN   64    // node inputs
#define NEDGE 128   // edge features
#define NOUTD 64    // node outputs
#define NITERS 7

typedef _Float16 half8 __attribute__((ext_vector_type(8)));
typedef _Float16 half4 __attribute__((ext_vector_type(4)));
typedef float floatx4 __attribute__((ext_vector_type(4)));

#define MFMA16(a,b,c) __builtin_amdgcn_mfma_f32_16x16x32_f16((a),(b),(c),0,0,0)

// async global->LDS, 16B per lane. LDS dest must be wave-uniform base (+lane*16 by HW).
__device__ __forceinline__ void load_lds16(const void* g, void* l){
  __builtin_amdgcn_global_load_lds(
      (__attribute__((address_space(1))) void*)(uintptr_t)g,
      (__attribute__((address_space(3))) void*)l,
      16, 0, 0);
}

// ---------------- weight repack: W (NOUT x KIN) f32 row-major -> [KIN/8][NOUT][8] f16 ----
__global__ void repack_kernel(const float* __restrict__ W, _Float16* __restrict__ out,
                              int NOUTp, int KINp){
  int g = blockIdx.x*256 + threadIdx.x;
  int total = NOUTp*(KINp>>3);
  if (g >= total) return;
  int c = g / NOUTp, j = g - c*NOUTp;
  #pragma unroll
  for (int i=0;i<8;++i) out[(size_t)g*8+i] = (_Float16)W[(size_t)j*KINp + c*8 + i];
}

__global__ void init_h_kernel(float* __restrict__ h32, _Float16* __restrict__ h16){
  int i = blockIdx.x*256 + threadIdx.x;   // grid covers N_NODES*NFEAT exactly
  h32[i]=0.f; h16[i]=(_Float16)0.f;
}
__global__ void init_gin_kernel(const float* __restrict__ ni, _Float16* __restrict__ gin){
  int i = blockIdx.x*256 + threadIdx.x;   // N_NODES*NIN
  if (i < N_NODES*NIN){
    int n = i>>6, j = i&63;
    gin[(size_t)n*192 + 128 + j] = (_Float16)ni[i];
  }
}
__global__ void zero_i32(int* __restrict__ p, int n){
  int i = blockIdx.x*256+threadIdx.x; if (i<n) p[i]=0;
}
__global__ void hist_kernel(const int* __restrict__ dst, int* __restrict__ cnt){
  int e = blockIdx.x*256+threadIdx.x; if (e<N_EDGES) atomicAdd(&cnt[dst[e]],1);
}
__global__ __launch_bounds__(1024) void scan_kernel(const int* __restrict__ cnt,
                                                    int* __restrict__ rowptr,
                                                    int* __restrict__ offs){
  __shared__ int sd[1024];
  int t = threadIdx.x;
  int c[16]; int s=0;
  #pragma unroll
  for (int k=0;k<16;++k){ c[k]=cnt[t*16+k]; s+=c[k]; }
  sd[t]=s; __syncthreads();
  for (int off=1; off<1024; off<<=1){
    int v = (t>=off)? sd[t-off]:0;
    __syncthreads();
    sd[t]+=v;
    __syncthreads();
  }
  int base = sd[t]-s; // exclusive prefix
  #pragma unroll
  for (int k=0;k<16;++k){ rowptr[t*16+k]=base; offs[t*16+k]=base; base+=c[k]; }
  if (t==0) rowptr[N_NODES]=N_EDGES;
}
__global__ void scatter_kernel(const int* __restrict__ dst, int* __restrict__ offs,
                               int* __restrict__ csr){
  int e = blockIdx.x*256+threadIdx.x;
  if (e<N_EDGES){ int p = atomicAdd(&offs[dst[e]],1); csr[p]=e; }
}

// ---------------- fused 4-layer edge MLP ----------------
// act LDS layout: [k/8 chunk][64 edges][8 halfs] -> all frag reads are contiguous b128.
// weight tile LDS layout per K-step: [kg 0..3][N][8].
template<int N>
__device__ __forceinline__ void stage_tile(const _Float16* Ws, int kk, _Float16* wb,
                                           int wave, int lane){
  const int TB = 4*N*16; // tile bytes
  const char* g = (const char*)Ws + (size_t)kk*TB;
  char* l = (char*)wb;
  #pragma unroll
  for (int ii=0; ii<TB/4096; ++ii){
    int off = ii*4096 + wave*1024;
    load_lds16(g + off + lane*16, l + off);
  }
}

template<int N, int NTW, int NEXTN>
__device__ __forceinline__ void run_layer(const _Float16* __restrict__ Ws,
                                          const _Float16* __restrict__ nextWs,
                                          const _Float16* act, _Float16* wbuf,
                                          int wave, int lane, floatx4 (&acc)[4][4]){
  const int kg = lane>>4, col = lane&15;
  const int j0 = wave*(N/4);
  for (int kk=0; kk<8; ++kk){
    __syncthreads();                 // tile kk staged+drained; prev buf free
    if (kk < 7) stage_tile<N>(Ws, kk+1, wbuf + ((kk+1)&1)*8192, wave, lane);
    else if constexpr (NEXTN > 0) stage_tile<NEXTN>(nextWs, 0, wbuf, wave, lane);
    const _Float16* wbc = wbuf + (kk&1)*8192;
    half8 a[4];
    #pragma unroll
    for (int mt=0; mt<4; ++mt)
      a[mt] = *(const half8*)&act[(((kk*4+kg)*64) + mt*16 + col)*8];
    #pragma unroll
    for (int nt=0; nt<NTW; ++nt){
      half8 b = *(const half8*)&wbc[(kg*N + j0 + nt*16 + col)*8];
      #pragma unroll
      for (int mt=0; mt<4; ++mt)
        acc[mt][nt] = MFMA16(a[mt], b, acc[mt][nt]);
    }
  }
}

__device__ __forceinline__ void epi_relu(floatx4 (&acc)[4][4], const float* __restrict__ bias,
                                         _Float16* act, int wave, int lane){
  const int rg = lane>>4, col = lane&15;
  #pragma unroll
  for (int nt=0; nt<4; ++nt){
    int j = wave*64 + nt*16 + col;
    float bv = bias[j];
    _Float16* dst = &act[((j>>3)*64)*8 + (j&7)];
    #pragma unroll
    for (int mt=0; mt<4; ++mt){
      #pragma unroll
      for (int r=0; r<4; ++r){
        int e = mt*16 + rg*4 + r;
        float v = acc[mt][nt][r] + bv;
        acc[mt][nt][r] = 0.f;
        v = fmaxf(v, 0.f);
        dst[(size_t)e*8] = (_Float16)v;
      }
    }
  }
}

__global__ __launch_bounds__(256) void msg_kernel(
    const _Float16* __restrict__ h,
    const int* __restrict__ src_ids, const int* __restrict__ dst_ids,
    const _Float16* __restrict__ W1s, const _Float16* __restrict__ W2s,
    const _Float16* __restrict__ W3s, const _Float16* __restrict__ W4s,
    const float* __restrict__ b1, const float* __restrict__ b2,
    const float* __restrict__ b3, const float* __restrict__ b4,
    _Float16* __restrict__ messages){
  __shared__ _Float16 act[32*64*8];    // 32 KB: [chunk][edge][8]
  __shared__ _Float16 wbuf[2*8192];    // 32 KB: double-buffered weight K-tiles
  const int t = threadIdx.x, wave = t>>6, lane = t&63;
  const int e0 = blockIdx.x*64;
  const int srow = src_ids[e0+lane]*NFEAT;
  const int drow = dst_ids[e0+lane]*NFEAT;
  // gather msg_in = [h[src] | h[dst]] into act (chunks 0..15 src, 16..31 dst)
  #pragma unroll
  for (int i=0;i<8;++i){
    int c = wave*8 + i;
    const _Float16* g = h + ((c<16) ? (srow + c*8) : (drow + (c-16)*8));
    load_lds16(g, (char*)act + (size_t)c*1024);
  }
  stage_tile<256>(W1s, 0, wbuf, wave, lane);
  floatx4 acc[4][4];
  const floatx4 fz = {0.f,0.f,0.f,0.f};
  #pragma unroll
  for (int i=0;i<4;++i)
    #pragma unroll
    for (int j=0;j<4;++j) acc[i][j] = fz;

  run_layer<256,4,256>(W1s, W2s, act, wbuf, wave, lane, acc);
  __syncthreads();
  epi_relu(acc, b1, act, wave, lane);
  run_layer<256,4,256>(W2s, W3s, act, wbuf, wave, lane, acc);
  __syncthreads();
  epi_relu(acc, b2, act, wave, lane);
  run_layer<256,4,128>(W3s, W4s, act, wbuf, wave, lane, acc);
  __syncthreads();
  epi_relu(acc, b3, act, wave, lane);
  run_layer<128,2,0>(W4s, nullptr, act, wbuf, wave, lane, acc);
  // L4 epilogue -> global messages (fp16, includes b4)
  const int rg = lane>>4, col = lane&15;
  #pragma unroll
  for (int nt=0; nt<2; ++nt){
    int j = wave*32 + nt*16 + col;
    float bv = b4[j];
    #pragma unroll
    for (int mt=0; mt<4; ++mt){
      #pragma unroll
      for (int r=0; r<4; ++r){
        int e = e0 + mt*16 + rg*4 + r;
        messages[(size_t)e*NEDGE + j] = (_Float16)(acc[mt][nt][r] + bv);
      }
    }
  }
}

// ---------------- CSR aggregation -> gru_in[:,0:128] ----------------
__global__ __launch_bounds__(256) void agg_kernel(const _Float16* __restrict__ messages,
    const int* __restrict__ rowptr, const int* __restrict__ csr,
    _Float16* __restrict__ gin){
  int t = threadIdx.x;
  int n = blockIdx.x*8 + (t>>5);
  int l4 = (t&31)*4;
  float a0=0,a1=0,a2=0,a3=0;
  int beg = rowptr[n], end = rowptr[n+1];
  for (int idx=beg; idx<end; ++idx){
    int e = csr[idx];
    half4 v = *(const half4*)(messages + (size_t)e*NEDGE + l4);
    a0 += (float)v.x; a1 += (float)v.y; a2 += (float)v.z; a3 += (float)v.w;
  }
  half4 o; o.x=(_Float16)a0; o.y=(_Float16)a1; o.z=(_Float16)a2; o.w=(_Float16)a3;
  *(half4*)(gin + (size_t)n*192 + l4) = o;
}

// ---------------- fused GRU + output projection ----------------
__device__ __forceinline__ void stage384(const _Float16* Ws, int kk, _Float16* wb,
                                         int wave, int lane){
  const char* g = (const char*)Ws + (size_t)kk*24576; // 4*384*16 bytes per K-step tile
  char* l = (char*)wb;
  #pragma unroll
  for (int ii=0; ii<6; ++ii){
    int off = ii*4096 + wave*1024;
    load_lds16(g + off + lane*16, l + off);
  }
}

__global__ __launch_bounds__(256,1) void gru_kernel(
    const _Float16* __restrict__ gin, _Float16* __restrict__ h16, float* __restrict__ h32,
    const _Float16* __restrict__ Wihs, const _Float16* __restrict__ Whhs,
    const _Float16* __restrict__ Wfs,
    const float* __restrict__ b_ih, const float* __restrict__ b_hh,
    const float* __restrict__ b_f,
    float* __restrict__ out){
  __shared__ _Float16 A1[24*64*8];   // gru_in rows (K=192)
  __shared__ _Float16 A2[16*64*8];   // h rows (K=128); later reused for h_new
  __shared__ _Float16 WB[2*12288];   // double-buffered 32x384 weight tiles
  __shared__ _Float16 WF[16*64*8];   // full W_f
  const int t = threadIdx.x, wave = t>>6, lane = t&63;
  const int kg = lane>>4, col = lane&15;
  const int n0 = blockIdx.x*64;
  #pragma unroll
  for (int ii=0; ii<6; ++ii){
    int c = ii*4 + wave;
    load_lds16((const char*)gin + (size_t)(n0+lane)*384 + c*16, (char*)A1 + (size_t)c*1024);
  }
  #pragma unroll
  for (int ii=0; ii<4; ++ii){
    int c = ii*4 + wave;
    load_lds16((const char*)h16 + (size_t)(n0+lane)*256 + c*16, (char*)A2 + (size_t)c*1024);
  }
  #pragma unroll
  for (int ii=0; ii<4; ++ii){
    int off = ii*4096 + wave*1024;
    load_lds16((const char*)Wfs + off + lane*16, (char*)WF + off);
  }
  stage384(Wihs, 0, WB, wave, lane);

  floatx4 gi[3][2][4], gh[3][2][4];
  const floatx4 fz = {0.f,0.f,0.f,0.f};
  #pragma unroll
  for (int g=0; g<3; ++g)
    #pragma unroll
    for (int nt=0; nt<2; ++nt)
      #pragma unroll
      for (int mt=0; mt<4; ++mt){ gi[g][nt][mt]=fz; gh[g][nt][mt]=fz; }

  // gi = gru_in @ W_ih^T   (K=192, 6 K-steps)
  for (int kk=0; kk<6; ++kk){
    __syncthreads();
    if (kk<5) stage384(Wihs, kk+1, WB + ((kk+1)&1)*12288, wave, lane);
    else      stage384(Whhs, 0, WB, wave, lane);   // (5+1)&1 == 0
    const _Float16* wbc = WB + (kk&1)*12288;
    half8 a[4];
    #pragma unroll
    for (int mt=0;mt<4;++mt)
      a[mt] = *(const half8*)&A1[(((kk*4+kg)*64) + mt*16 + col)*8];
    #pragma unroll
    for (int g=0; g<3; ++g)
      #pragma unroll
      for (int nt=0; nt<2; ++nt){
        int j = g*128 + wave*32 + nt*16 + col;
        half8 b = *(const half8*)&wbc[(kg*384 + j)*8];
        #pragma unroll
        for (int mt=0;mt<4;++mt)
          gi[g][nt][mt] = MFMA16(a[mt], b, gi[g][nt][mt]);
      }
  }
  // gh = h @ W_hh^T   (K=128, 4 K-steps)
  for (int kk=0; kk<4; ++kk){
    __syncthreads();
    if (kk<3) stage384(Whhs, kk+1, WB + ((kk+1)&1)*12288, wave, lane);
    const _Float16* wbc = WB + (kk&1)*12288;
    half8 a[4];
    #pragma unroll
    for (int mt=0;mt<4;++mt)
      a[mt] = *(const half8*)&A2[(((kk*4+kg)*64) + mt*16 + col)*8];
    #pragma unroll
    for (int g=0; g<3; ++g)
      #pragma unroll
      for (int nt=0; nt<2; ++nt){
        int j = g*128 + wave*32 + nt*16 + col;
        half8 b = *(const half8*)&wbc[(kg*384 + j)*8];
        #pragma unroll
        for (int mt=0;mt<4;++mt)
          gh[g][nt][mt] = MFMA16(a[mt], b, gh[g][nt][mt]);
      }
  }
  __syncthreads();   // all A2 (h_old) fragment reads done before overwrite

  // gates + h update; h_new goes to global (f32+f16) and into A2 for the W_f GEMM
  #pragma unroll
  for (int nt=0; nt<2; ++nt){
    int jl = wave*32 + nt*16 + col;     // 0..127
    float bir=b_ih[jl], biz=b_ih[128+jl], bin_=b_ih[256+jl];
    float bhr=b_hh[jl], bhz=b_hh[128+jl], bhn=b_hh[256+jl];
    #pragma unroll
    for (int mt=0; mt<4; ++mt){
      #pragma unroll
      for (int r=0; r<4; ++r){
        int e = mt*16 + kg*4 + r;
        float ir = gi[0][nt][mt][r] + bir;
        float iz = gi[1][nt][mt][r] + biz;
        float inn= gi[2][nt][mt][r] + bin_;
        float hr = gh[0][nt][mt][r] + bhr;
        float hz = gh[1][nt][mt][r] + bhz;
        float hn = gh[2][nt][mt][r] + bhn;
        float rg2 = 1.f/(1.f+__expf(-(ir+hr)));
        float zg  = 1.f/(1.f+__expf(-(iz+hz)));
        float ng  = tanhf(inn + rg2*hn);
        size_t hidx = (size_t)(n0+e)*NFEAT + jl;
        float hnew = (1.f-zg)*ng + zg*h32[hidx];
        h32[hidx] = hnew;
        h16[hidx] = (_Float16)hnew;
        A2[(((jl>>3)*64) + e)*8 + (jl&7)] = (_Float16)hnew;
      }
    }
  }
  __syncthreads();

  // out = h_new @ W_f^T + b_f  (K=128 -> 64 cols; wave w owns cols w*16..+16)
  floatx4 facc[4];
  #pragma unroll
  for (int mt=0;mt<4;++mt) facc[mt]=fz;
  for (int kk=0; kk<4; ++kk){
    half8 a[4];
    #pragma unroll
    for (int mt=0;mt<4;++mt)
      a[mt] = *(const half8*)&A2[(((kk*4+kg)*64) + mt*16 + col)*8];
    half8 b = *(const half8*)&WF[(((kk*4+kg)*64) + wave*16 + col)*8];
    #pragma unroll
    for (int mt=0;mt<4;++mt)
      facc[mt] = MFMA16(a[mt], b, facc[mt]);
  }
  float bf = b_f[wave*16+col];
  #pragma unroll
  for (int mt=0; mt<4; ++mt){
    #pragma unroll
    for (int r=0; r<4; ++r){
      int e = mt*16 + kg*4 + r;
      out[(size_t)(n0+e)*NOUTD + wave*16 + col] = facc[mt][r] + bf;
    }
  }
}

// ---------------- launch ----------------
extern "C" void kernel_launch(void* const* d_in, const int* in_sizes, int n_in,
                              void* d_out, int out_size, void* d_ws, size_t ws_size,
                              hipStream_t stream){
  (void)in_sizes; (void)n_in; (void)out_size; (void)ws_size;
  const float* node_inputs = (const float*)d_in[0];
  const int*   src_ids = (const int*)d_in[1];
  const int*   dst_ids = (const int*)d_in[2];
  const float* W1 = (const float*)d_in[3];  const float* b1 = (const float*)d_in[4];
  const float* W2 = (const float*)d_in[5];  const float* b2 = (const float*)d_in[6];
  const float* W3 = (const float*)d_in[7];  const float* b3 = (const float*)d_in[8];
  const float* W4 = (const float*)d_in[9];  const float* b4 = (const float*)d_in[10];
  const float* W_ih = (const float*)d_in[11];
  const float* W_hh = (const float*)d_in[12];
  const float* b_ih = (const float*)d_in[13];
  const float* b_hh = (const float*)d_in[14];
  const float* W_f  = (const float*)d_in[15];
  const float* b_f  = (const float*)d_in[16];
  float* out = (float*)d_out;

  char* ws = (char*)d_ws;
  auto alloc = [&](size_t b){ char* p = ws; ws += (b + 255) & ~(size_t)255; return p; };
  _Float16* h16  = (_Float16*)alloc((size_t)N_NODES*NFEAT*2);
  float*    h32  = (float*)   alloc((size_t)N_NODES*NFEAT*4);
  _Float16* gin  = (_Float16*)alloc((size_t)N_NODES*192*2);
  _Float16* msgs = (_Float16*)alloc((size_t)N_EDGES*NEDGE*2);
  _Float16* W1s  = (_Float16*)alloc(256*256*2);
  _Float16* W2s  = (_Float16*)alloc(256*256*2);
  _Float16* W3s  = (_Float16*)alloc(256*256*2);
  _Float16* W4s  = (_Float16*)alloc(128*256*2);
  _Float16* Wihs = (_Float16*)alloc(384*192*2);
  _Float16* Whhs = (_Float16*)alloc(384*128*2);
  _Float16* Wfs  = (_Float16*)alloc(64*128*2);
  int* cnt    = (int*)alloc((size_t)N_NODES*4);
  int* rowptr = (int*)alloc((size_t)(N_NODES+1)*4);
  int* offs   = (int*)alloc((size_t)N_NODES*4);
  int* csr    = (int*)alloc((size_t)N_EDGES*4);

  repack_kernel<<<32,256,0,stream>>>(W1, W1s, 256, 256);
  repack_kernel<<<32,256,0,stream>>>(W2, W2s, 256, 256);
  repack_kernel<<<32,256,0,stream>>>(W3, W3s, 256, 256);
  repack_kernel<<<16,256,0,stream>>>(W4, W4s, 128, 256);
  repack_kernel<<<36,256,0,stream>>>(W_ih, Wihs, 384, 192);
  repack_kernel<<<24,256,0,stream>>>(W_hh, Whhs, 384, 128);
  repack_kernel<<<4,256,0,stream>>>(W_f, Wfs, 64, 128);
  init_h_kernel<<<(N_NODES*NFEAT)/256,256,0,stream>>>(h32, h16);
  init_gin_kernel<<<(N_NODES*NIN)/256,256,0,stream>>>(node_inputs, gin);
  zero_i32<<<N_NODES/256,256,0,stream>>>(cnt, N_NODES);
  hist_kernel<<<N_EDGES/256,256,0,stream>>>(dst_ids, cnt);
  scan_kernel<<<1,1024,0,stream>>>(cnt, rowptr, offs);
  scatter_kernel<<<N_EDGES/256,256,0,stream>>>(dst_ids, offs, csr);

  for (int it=0; it<NITERS; ++it){
    msg_kernel<<<N_EDGES/64,256,0,stream>>>(h16, src_ids, dst_ids,
                                            W1s,W2s,W3s,W4s, b1,b2,b3,b4, msgs);
    agg_kernel<<<N_NODES/8,256,0,stream>>>(msgs, rowptr, csr, gin);
    gru_kernel<<<N_NODES/64,256,0,stream>>>(gin, h16, h32, Wihs, Whhs, Wfs,
                                            b_ih, b_hh, b_f,
                                            out + (size_t)it*N_NODES*NOUTD);
  }
}

// Round 3
// 542.464 us; speedup vs baseline: 1.1125x; 1.1125x over previous
//
#include <hip/hip_runtime.h>
#include <cstdint>
#include <cstddef>

#define N_NODES 16384
#define N_EDGES 65536
#define NFEAT 128   // GRU hidden
#define NIN   64    // node inputs
#define NEDGE 128   // edge features
#define NOUTD 64    // node outputs
#define NITERS 7

typedef _Float16 half8 __attribute__((ext_vector_type(8)));
typedef _Float16 half4 __attribute__((ext_vector_type(4)));
typedef float floatx4 __attribute__((ext_vector_type(4)));

#define MFMA16(a,b,c) __builtin_amdgcn_mfma_f32_16x16x32_f16((a),(b),(c),0,0,0)

// async global->LDS, 16B per lane. LDS dest is wave-uniform base (+lane*16 by HW).
__device__ __forceinline__ void load_lds16(const void* g, void* l){
  __builtin_amdgcn_global_load_lds(
      (__attribute__((address_space(1))) void*)(uintptr_t)g,
      (__attribute__((address_space(3))) void*)l,
      16, 0, 0);
}

// ---------------- weight repack: W (NOUT x KIN) f32 row-major -> [KIN/8][NOUT][8] f16 ----
__global__ void repack_kernel(const float* __restrict__ W, _Float16* __restrict__ out,
                              int NOUTp, int KINp){
  int g = blockIdx.x*256 + threadIdx.x;
  int total = NOUTp*(KINp>>3);
  if (g >= total) return;
  int c = g / NOUTp, j = g - c*NOUTp;
  #pragma unroll
  for (int i=0;i<8;++i) out[(size_t)g*8+i] = (_Float16)W[(size_t)j*KINp + c*8 + i];
}

__global__ void init_h_kernel(float* __restrict__ h32, _Float16* __restrict__ h16){
  int i = blockIdx.x*256 + threadIdx.x;   // grid covers N_NODES*NFEAT exactly
  h32[i]=0.f; h16[i]=(_Float16)0.f;
}
__global__ void init_gin_kernel(const float* __restrict__ ni, _Float16* __restrict__ gin){
  int i = blockIdx.x*256 + threadIdx.x;   // N_NODES*NIN
  if (i < N_NODES*NIN){
    int n = i>>6, j = i&63;
    gin[(size_t)n*192 + 128 + j] = (_Float16)ni[i];
  }
}
__global__ void zero_i32(int* __restrict__ p, int n){
  int i = blockIdx.x*256+threadIdx.x; if (i<n) p[i]=0;
}
__global__ void hist_kernel(const int* __restrict__ dst, int* __restrict__ cnt){
  int e = blockIdx.x*256+threadIdx.x; if (e<N_EDGES) atomicAdd(&cnt[dst[e]],1);
}
__global__ __launch_bounds__(1024) void scan_kernel(const int* __restrict__ cnt,
                                                    int* __restrict__ rowptr,
                                                    int* __restrict__ offs){
  __shared__ int sd[1024];
  int t = threadIdx.x;
  int c[16]; int s=0;
  #pragma unroll
  for (int k=0;k<16;++k){ c[k]=cnt[t*16+k]; s+=c[k]; }
  sd[t]=s; __syncthreads();
  for (int off=1; off<1024; off<<=1){
    int v = (t>=off)? sd[t-off]:0;
    __syncthreads();
    sd[t]+=v;
    __syncthreads();
  }
  int base = sd[t]-s; // exclusive prefix
  #pragma unroll
  for (int k=0;k<16;++k){ rowptr[t*16+k]=base; offs[t*16+k]=base; base+=c[k]; }
  if (t==0) rowptr[N_NODES]=N_EDGES;
}
__global__ void scatter_kernel(const int* __restrict__ dst, int* __restrict__ offs,
                               int* __restrict__ csr){
  int e = blockIdx.x*256+threadIdx.x;
  if (e<N_EDGES){ int p = atomicAdd(&offs[dst[e]],1); csr[p]=e; }
}

// ---------------- fused 4-layer edge MLP, 256 edges/block, 8 waves ----------------
// act LDS layout: [k/8 chunk][256 edges][8 halfs] -> all frag reads contiguous b128.
// weight tile LDS layout per K-step: [kg 0..3][N][8].
// NOTE: one N=256 K-step tile = 4*256*16 B = 16 KB -> double-buffer stride MUST be
// 8192 halfs (16 KB). Round-2 bug: stride 4096 halfs overlapped the two buffers.
template<int N>
__device__ __forceinline__ void stage_tile(const _Float16* Ws, int kk, _Float16* wb,
                                           int wave, int lane){
  constexpr int TB = 4*N*16; // tile bytes (K=32 x N x 2B)
  const char* g = (const char*)Ws + (size_t)kk*TB;
  char* l = (char*)wb;
  #pragma unroll
  for (int ii=0; ii<TB/8192; ++ii){
    int off = ii*8192 + wave*1024;
    load_lds16(g + off + lane*16, l + off);
  }
}

template<int N, int NTW, int NEXTN>
__device__ __forceinline__ void run_layer(const _Float16* __restrict__ Ws,
                                          const _Float16* __restrict__ nextWs,
                                          const _Float16* act, _Float16* wbuf,
                                          int wave, int lane, floatx4 (&acc)[8][4]){
  const int kg = lane>>4, col = lane&15;
  const int wr = wave>>2, wc = wave&3;   // 2M x 4N wave grid
  const int j0 = wc*(N/4);
  const int r0 = wr*128;
  for (int kk=0; kk<8; ++kk){
    __syncthreads();                 // tile kk staged+drained; prev buf free
    if (kk < 7) stage_tile<N>(Ws, kk+1, wbuf + ((kk+1)&1)*8192, wave, lane);
    else if constexpr (NEXTN > 0) stage_tile<NEXTN>(nextWs, 0, wbuf, wave, lane);
    const _Float16* wbc = wbuf + (kk&1)*8192;
    half8 a[8];
    #pragma unroll
    for (int mt=0; mt<8; ++mt)
      a[mt] = *(const half8*)&act[(((kk*4+kg)*256) + r0 + mt*16 + col)*8];
    #pragma unroll
    for (int nt=0; nt<NTW; ++nt){
      half8 b = *(const half8*)&wbc[(kg*N + j0 + nt*16 + col)*8];
      #pragma unroll
      for (int mt=0; mt<8; ++mt)
        acc[mt][nt] = MFMA16(a[mt], b, acc[mt][nt]);
    }
  }
}

__device__ __forceinline__ void epi_relu(floatx4 (&acc)[8][4], const float* __restrict__ bias,
                                         _Float16* act, int wave, int lane){
  const int rg = lane>>4, col = lane&15;
  const int wr = wave>>2, wc = wave&3;
  #pragma unroll
  for (int nt=0; nt<4; ++nt){
    int j = wc*64 + nt*16 + col;
    float bv = bias[j];
    _Float16* dst = &act[(size_t)(j>>3)*2048 + (j&7)];
    #pragma unroll
    for (int mt=0; mt<8; ++mt){
      #pragma unroll
      for (int r=0; r<4; ++r){
        int e = wr*128 + mt*16 + rg*4 + r;
        float v = acc[mt][nt][r] + bv;
        acc[mt][nt][r] = 0.f;
        v = fmaxf(v, 0.f);
        dst[(size_t)e*8] = (_Float16)v;
      }
    }
  }
}

__global__ __launch_bounds__(512,2) void msg_kernel(
    const _Float16* __restrict__ h,
    const int* __restrict__ src_ids, const int* __restrict__ dst_ids,
    const _Float16* __restrict__ W1s, const _Float16* __restrict__ W2s,
    const _Float16* __restrict__ W3s, const _Float16* __restrict__ W4s,
    const float* __restrict__ b1, const float* __restrict__ b2,
    const float* __restrict__ b3, const float* __restrict__ b4,
    _Float16* __restrict__ messages){
  __shared__ _Float16 act[32*256*8];   // 128 KB: [chunk][edge][8]
  __shared__ _Float16 wbuf[2*8192];    // 32 KB: double-buffered 16 KB weight K-tiles
  const int t = threadIdx.x, wave = t>>6, lane = t&63;
  const int e0 = blockIdx.x*256;
  // gather msg_in = [h[src] | h[dst]] into act (chunks 0..15 src, 16..31 dst)
  // wave w: edge group eg=w>>1 (64 edges), half hf=w&1 (0=src, 1=dst)
  {
    const int eg = wave>>1, hf = wave&1;
    const int edge = e0 + eg*64 + lane;
    const int row = (hf ? dst_ids[edge] : src_ids[edge]) * NFEAT;
    #pragma unroll
    for (int i=0;i<16;++i){
      int c = hf*16 + i;
      load_lds16(h + row + i*8, (char*)act + ((size_t)c*256 + eg*64)*16);
    }
  }
  stage_tile<256>(W1s, 0, wbuf, wave, lane);
  floatx4 acc[8][4];
  const floatx4 fz = {0.f,0.f,0.f,0.f};
  #pragma unroll
  for (int i=0;i<8;++i)
    #pragma unroll
    for (int j=0;j<4;++j) acc[i][j] = fz;

  run_layer<256,4,256>(W1s, W2s, act, wbuf, wave, lane, acc);
  __syncthreads();
  epi_relu(acc, b1, act, wave, lane);
  run_layer<256,4,256>(W2s, W3s, act, wbuf, wave, lane, acc);
  __syncthreads();
  epi_relu(acc, b2, act, wave, lane);
  run_layer<256,4,128>(W3s, W4s, act, wbuf, wave, lane, acc);
  __syncthreads();
  epi_relu(acc, b3, act, wave, lane);
  run_layer<128,2,0>(W4s, nullptr, act, wbuf, wave, lane, acc);
  // L4 epilogue -> global messages (fp16, includes b4); wave cols = wc*32..+32
  const int rg = lane>>4, col = lane&15;
  const int wr = wave>>2, wc = wave&3;
  #pragma unroll
  for (int nt=0; nt<2; ++nt){
    int j = wc*32 + nt*16 + col;
    float bv = b4[j];
    #pragma unroll
    for (int mt=0; mt<8; ++mt){
      #pragma unroll
      for (int r=0; r<4; ++r){
        int e = e0 + wr*128 + mt*16 + rg*4 + r;
        messages[(size_t)e*NEDGE + j] = (_Float16)(acc[mt][nt][r] + bv);
      }
    }
  }
}

// ---------------- CSR aggregation -> gru_in[:,0:128] ----------------
__global__ __launch_bounds__(256) void agg_kernel(const _Float16* __restrict__ messages,
    const int* __restrict__ rowptr, const int* __restrict__ csr,
    _Float16* __restrict__ gin){
  int t = threadIdx.x;
  int n = blockIdx.x*8 + (t>>5);
  int l4 = (t&31)*4;
  float a0=0,a1=0,a2=0,a3=0;
  int beg = rowptr[n], end = rowptr[n+1];
  for (int idx=beg; idx<end; ++idx){
    int e = csr[idx];
    half4 v = *(const half4*)(messages + (size_t)e*NEDGE + l4);
    a0 += (float)v.x; a1 += (float)v.y; a2 += (float)v.z; a3 += (float)v.w;
  }
  half4 o; o.x=(_Float16)a0; o.y=(_Float16)a1; o.z=(_Float16)a2; o.w=(_Float16)a3;
  *(half4*)(gin + (size_t)n*192 + l4) = o;
}

// ---------------- fused GRU + output projection ----------------
__device__ __forceinline__ void stage384(const _Float16* Ws, int kk, _Float16* wb,
                                         int wave, int lane){
  const char* g = (const char*)Ws + (size_t)kk*24576; // 4*384*16 bytes per K-step tile
  char* l = (char*)wb;
  #pragma unroll
  for (int ii=0; ii<6; ++ii){
    int off = ii*4096 + wave*1024;
    load_lds16(g + off + lane*16, l + off);
  }
}

__global__ __launch_bounds__(256,1) void gru_kernel(
    const _Float16* __restrict__ gin, _Float16* __restrict__ h16, float* __restrict__ h32,
    const _Float16* __restrict__ Wihs, const _Float16* __restrict__ Whhs,
    const _Float16* __restrict__ Wfs,
    const float* __restrict__ b_ih, const float* __restrict__ b_hh,
    const float* __restrict__ b_f,
    float* __restrict__ out){
  __shared__ _Float16 A1[24*64*8];   // gru_in rows (K=192)
  __shared__ _Float16 A2[16*64*8];   // h rows (K=128); later reused for h_new
  __shared__ _Float16 WB[2*12288];   // double-buffered 32x384 weight tiles
  __shared__ _Float16 WF[16*64*8];   // full W_f
  const int t = threadIdx.x, wave = t>>6, lane = t&63;
  const int kg = lane>>4, col = lane&15;
  const int n0 = blockIdx.x*64;
  #pragma unroll
  for (int ii=0; ii<6; ++ii){
    int c = ii*4 + wave;
    load_lds16((const char*)gin + (size_t)(n0+lane)*384 + c*16, (char*)A1 + (size_t)c*1024);
  }
  #pragma unroll
  for (int ii=0; ii<4; ++ii){
    int c = ii*4 + wave;
    load_lds16((const char*)h16 + (size_t)(n0+lane)*256 + c*16, (char*)A2 + (size_t)c*1024);
  }
  #pragma unroll
  for (int ii=0; ii<4; ++ii){
    int off = ii*4096 + wave*1024;
    load_lds16((const char*)Wfs + off + lane*16, (char*)WF + off);
  }
  stage384(Wihs, 0, WB, wave, lane);

  floatx4 gi[3][2][4], gh[3][2][4];
  const floatx4 fz = {0.f,0.f,0.f,0.f};
  #pragma unroll
  for (int g=0; g<3; ++g)
    #pragma unroll
    for (int nt=0; nt<2; ++nt)
      #pragma unroll
      for (int mt=0; mt<4; ++mt){ gi[g][nt][mt]=fz; gh[g][nt][mt]=fz; }

  // gi = gru_in @ W_ih^T   (K=192, 6 K-steps)
  for (int kk=0; kk<6; ++kk){
    __syncthreads();
    if (kk<5) stage384(Wihs, kk+1, WB + ((kk+1)&1)*12288, wave, lane);
    else      stage384(Whhs, 0, WB, wave, lane);   // (5+1)&1 == 0
    const _Float16* wbc = WB + (kk&1)*12288;
    half8 a[4];
    #pragma unroll
    for (int mt=0;mt<4;++mt)
      a[mt] = *(const half8*)&A1[(((kk*4+kg)*64) + mt*16 + col)*8];
    #pragma unroll
    for (int g=0; g<3; ++g)
      #pragma unroll
      for (int nt=0; nt<2; ++nt){
        int j = g*128 + wave*32 + nt*16 + col;
        half8 b = *(const half8*)&wbc[(kg*384 + j)*8];
        #pragma unroll
        for (int mt=0;mt<4;++mt)
          gi[g][nt][mt] = MFMA16(a[mt], b, gi[g][nt][mt]);
      }
  }
  // gh = h @ W_hh^T   (K=128, 4 K-steps)
  for (int kk=0; kk<4; ++kk){
    __syncthreads();
    if (kk<3) stage384(Whhs, kk+1, WB + ((kk+1)&1)*12288, wave, lane);
    const _Float16* wbc = WB + (kk&1)*12288;
    half8 a[4];
    #pragma unroll
    for (int mt=0;mt<4;++mt)
      a[mt] = *(const half8*)&A2[(((kk*4+kg)*64) + mt*16 + col)*8];
    #pragma unroll
    for (int g=0; g<3; ++g)
      #pragma unroll
      for (int nt=0; nt<2; ++nt){
        int j = g*128 + wave*32 + nt*16 + col;
        half8 b = *(const half8*)&wbc[(kg*384 + j)*8];
        #pragma unroll
        for (int mt=0;mt<4;++mt)
          gh[g][nt][mt] = MFMA16(a[mt], b, gh[g][nt][mt]);
      }
  }
  __syncthreads();   // all A2 (h_old) fragment reads done before overwrite

  // gates + h update; h_new goes to global (f32+f16) and into A2 for the W_f GEMM
  #pragma unroll
  for (int nt=0; nt<2; ++nt){
    int jl = wave*32 + nt*16 + col;     // 0..127
    float bir=b_ih[jl], biz=b_ih[128+jl], bin_=b_ih[256+jl];
    float bhr=b_hh[jl], bhz=b_hh[128+jl], bhn=b_hh[256+jl];
    #pragma unroll
    for (int mt=0; mt<4; ++mt){
      #pragma unroll
      for (int r=0; r<4; ++r){
        int e = mt*16 + kg*4 + r;
        float ir = gi[0][nt][mt][r] + bir;
        float iz = gi[1][nt][mt][r] + biz;
        float inn= gi[2][nt][mt][r] + bin_;
        float hr = gh[0][nt][mt][r] + bhr;
        float hz = gh[1][nt][mt][r] + bhz;
        float hn = gh[2][nt][mt][r] + bhn;
        float rg2 = 1.f/(1.f+__expf(-(ir+hr)));
        float zg  = 1.f/(1.f+__expf(-(iz+hz)));
        float ng  = tanhf(inn + rg2*hn);
        size_t hidx = (size_t)(n0+e)*NFEAT + jl;
        float hnew = (1.f-zg)*ng + zg*h32[hidx];
        h32[hidx] = hnew;
        h16[hidx] = (_Float16)hnew;
        A2[(((jl>>3)*64) + e)*8 + (jl&7)] = (_Float16)hnew;
      }
    }
  }
  __syncthreads();

  // out = h_new @ W_f^T + b_f  (K=128 -> 64 cols; wave w owns cols w*16..+16)
  floatx4 facc[4];
  #pragma unroll
  for (int mt=0;mt<4;++mt) facc[mt]=fz;
  for (int kk=0; kk<4; ++kk){
    half8 a[4];
    #pragma unroll
    for (int mt=0;mt<4;++mt)
      a[mt] = *(const half8*)&A2[(((kk*4+kg)*64) + mt*16 + col)*8];
    half8 b = *(const half8*)&WF[(((kk*4+kg)*64) + wave*16 + col)*8];
    #pragma unroll
    for (int mt=0;mt<4;++mt)
      facc[mt] = MFMA16(a[mt], b, facc[mt]);
  }
  float bf = b_f[wave*16+col];
  #pragma unroll
  for (int mt=0; mt<4; ++mt){
    #pragma unroll
    for (int r=0; r<4; ++r){
      int e = mt*16 + kg*4 + r;
      out[(size_t)(n0+e)*NOUTD + wave*16 + col] = facc[mt][r] + bf;
    }
  }
}

// ---------------- launch ----------------
extern "C" void kernel_launch(void* const* d_in, const int* in_sizes, int n_in,
                              void* d_out, int out_size, void* d_ws, size_t ws_size,
                              hipStream_t stream){
  (void)in_sizes; (void)n_in; (void)out_size; (void)ws_size;
  const float* node_inputs = (const float*)d_in[0];
  const int*   src_ids = (const int*)d_in[1];
  const int*   dst_ids = (const int*)d_in[2];
  const float* W1 = (const float*)d_in[3];  const float* b1 = (const float*)d_in[4];
  const float* W2 = (const float*)d_in[5];  const float* b2 = (const float*)d_in[6];
  const float* W3 = (const float*)d_in[7];  const float* b3 = (const float*)d_in[8];
  const float* W4 = (const float*)d_in[9];  const float* b4 = (const float*)d_in[10];
  const float* W_ih = (const float*)d_in[11];
  const float* W_hh = (const float*)d_in[12];
  const float* b_ih = (const float*)d_in[13];
  const float* b_hh = (const float*)d_in[14];
  const float* W_f  = (const float*)d_in[15];
  const float* b_f  = (const float*)d_in[16];
  float* out = (float*)d_out;

  char* ws = (char*)d_ws;
  auto alloc = [&](size_t b){ char* p = ws; ws += (b + 255) & ~(size_t)255; return p; };
  _Float16* h16  = (_Float16*)alloc((size_t)N_NODES*NFEAT*2);
  float*    h32  = (float*)   alloc((size_t)N_NODES*NFEAT*4);
  _Float16* gin  = (_Float16*)alloc((size_t)N_NODES*192*2);
  _Float16* msgs = (_Float16*)alloc((size_t)N_EDGES*NEDGE*2);
  _Float16* W1s  = (_Float16*)alloc(256*256*2);
  _Float16* W2s  = (_Float16*)alloc(256*256*2);
  _Float16* W3s  = (_Float16*)alloc(256*256*2);
  _Float16* W4s  = (_Float16*)alloc(128*256*2);
  _Float16* Wihs = (_Float16*)alloc(384*192*2);
  _Float16* Whhs = (_Float16*)alloc(384*128*2);
  _Float16* Wfs  = (_Float16*)alloc(64*128*2);
  int* cnt    = (int*)alloc((size_t)N_NODES*4);
  int* rowptr = (int*)alloc((size_t)(N_NODES+1)*4);
  int* offs   = (int*)alloc((size_t)N_NODES*4);
  int* csr    = (int*)alloc((size_t)N_EDGES*4);

  repack_kernel<<<32,256,0,stream>>>(W1, W1s, 256, 256);
  repack_kernel<<<32,256,0,stream>>>(W2, W2s, 256, 256);
  repack_kernel<<<32,256,0,stream>>>(W3, W3s, 256, 256);
  repack_kernel<<<16,256,0,stream>>>(W4, W4s, 128, 256);
  repack_kernel<<<36,256,0,stream>>>(W_ih, Wihs, 384, 192);
  repack_kernel<<<24,256,0,stream>>>(W_hh, Whhs, 384, 128);
  repack_kernel<<<4,256,0,stream>>>(W_f, Wfs, 64, 128);
  init_h_kernel<<<(N_NODES*NFEAT)/256,256,0,stream>>>(h32, h16);
  init_gin_kernel<<<(N_NODES*NIN)/256,256,0,stream>>>(node_inputs, gin);
  zero_i32<<<N_NODES/256,256,0,stream>>>(cnt, N_NODES);
  hist_kernel<<<N_EDGES/256,256,0,stream>>>(dst_ids, cnt);
  scan_kernel<<<1,1024,0,stream>>>(cnt, rowptr, offs);
  scatter_kernel<<<N_EDGES/256,256,0,stream>>>(dst_ids, offs, csr);

  for (int it=0; it<NITERS; ++it){
    msg_kernel<<<N_EDGES/256,512,0,stream>>>(h16, src_ids, dst_ids,
                                             W1s,W2s,W3s,W4s, b1,b2,b3,b4, msgs);
    agg_kernel<<<N_NODES/8,256,0,stream>>>(msgs, rowptr, csr, gin);
    gru_kernel<<<N_NODES/64,256,0,stream>>>(gin, h16, h32, Wihs, Whhs, Wfs,
                                            b_ih, b_hh, b_f,
                                            out + (size_t)it*N_NODES*NOUTD);
  }
}